// Round 2
// baseline (599.443 us; speedup 1.0000x reference)
//
#include <hip/hip_runtime.h>
#include <cstdint>

// ---------------------------------------------------------------------------
// AdaptiveMixing fused kernel set, R2.
// R2 changes vs R1:
//  - lane-linear LDS layouts (pt/smT/g1s) -> kill 3.9e7 bank conflicts
//  - branchless A-S erf gelu (rcp+exp, ~16 insts) replaces erff
//  - spatial stage processes d in pairs of tiles (full 16-lane n)
//  - y2 layout k'' = dt2*512 + d16*32 + o -> full-line uint2 stores
//    (wob permuted to k'' in prep so outproj stays a clean GEMM)
//  - outproj: full-K (4096), no atomics, 512 wgs x 256 thr, tile 32x128
// MFMA 16x16x32_bf16: A/B: idx lane&15, k=(lane>>4)*8+j; C/D: col=lane&15,
// row=(lane>>4)*4+i.
// ---------------------------------------------------------------------------

typedef __bf16 bf16x8 __attribute__((ext_vector_type(8)));
typedef float  f32x4  __attribute__((ext_vector_type(4)));
typedef unsigned short ushort;
typedef ushort ushort8 __attribute__((ext_vector_type(8)));

#define TW 16     // tokens per workgroup (fused)

__device__ __forceinline__ ushort f2b(float f) {
    union { float f; uint32_t u; } v; v.f = f;
    uint32_t u = v.u;
    u += 0x7fffu + ((u >> 16) & 1u);   // RNE
    return (ushort)(u >> 16);
}
__device__ __forceinline__ uint32_t pk2(float a, float b) {
    return (uint32_t)f2b(a) | ((uint32_t)f2b(b) << 16);
}
// Abramowitz-Stegun 7.1.26 erf (|err|<=1.5e-7), branchless; gelu exact form.
__device__ __forceinline__ float gelu_fast(float x) {
    float z = fabsf(x) * 0.70710678118654752440f;
    float t = __builtin_amdgcn_rcpf(fmaf(0.3275911f, z, 1.0f));
    float p = t * fmaf(t, fmaf(t, fmaf(t, fmaf(t, 1.061405429f, -1.453152027f),
                                       1.421413741f), -0.284496736f), 0.254829592f);
    float e = __expf(-z * z);
    float erfv = copysignf(fmaf(-p, e, 1.0f), x);
    return 0.5f * x * (1.0f + erfv);
}

// ---------------------------------------------------------------------------
// prep: bf16 copies of w1/w2; wo -> bf16 permuted to k'' order.
// k'' = dt2*512 + d16*32 + o  <->  k = o*128 + dt2*16 + d16
__global__ void prep(const float* __restrict__ w2, const float* __restrict__ w1,
                     const float* __restrict__ wo,
                     ushort* __restrict__ w2b, ushort* __restrict__ w1b,
                     ushort* __restrict__ wob) {
    int i = blockIdx.x * 256 + threadIdx.x;          // 1,114,112 threads
    if (i < 1114112) w2b[i] = f2b(w2[i]);            // [17408][64]
    if (i < 16384)   w1b[i] = f2b(w1[i]);            // [64][256]
    if (i < 1048576) {
        int q = i >> 12, r = i & 4095;
        int dt2 = r >> 9, d16 = (r >> 5) & 15, o = r & 31;
        wob[i] = f2b(wo[q * 4096 + o * 128 + dt2 * 16 + d16]);
    }
}

// ---------------------------------------------------------------------------
__launch_bounds__(512, 4)
__global__ void fused(const float* __restrict__ sampled, const float* __restrict__ query,
                      const float* __restrict__ ln_w, const float* __restrict__ ln_b,
                      const float* __restrict__ b1, const float* __restrict__ b2,
                      const float* __restrict__ m_beta, const float* __restrict__ s_beta,
                      const ushort* __restrict__ w2b, const ushort* __restrict__ w1b,
                      ushort* __restrict__ y2) {
    __shared__ ushort Hb[TW * 64];                       // h bf16 [t][64]
    __shared__ union {
        ushort qn[TW * 264];                             // phase 1: LN out
        ushort smT[TW * 1032];                           // phase 2: sm [t][o*32+p]
        struct {
            ushort pt[TW * 1032];                        // [t][chunk(c>>3,dd)][c&7]
            ushort g1s[TW * 640];                        // [t][d16*40+p]
        } mp;                                            // main loop
    } U;
    __shared__ float mb_s[128];
    __shared__ float sb_s[32];

    const int tid  = threadIdx.x;
    const int wv   = tid >> 6;          // wave 0..7
    const int lane = tid & 63;
    const int lq   = lane >> 4;         // quad
    const int ln16 = lane & 15;
    const int tok0 = blockIdx.x * TW;

    if (tid < 128) mb_s[tid] = m_beta[tid];
    else if (tid < 160) sb_s[tid - 128] = s_beta[tid - 128];

    // ---- step 1: LayerNorm, 2 tokens per wave; qn -> LDS bf16 (row 264)
    for (int tt = 0; tt < 2; ++tt) {
        int t = wv * 2 + tt;
        const float* q = query + (size_t)(tok0 + t) * 256;
        float2 a = *(const float2*)(q + 2 * lane);
        float2 b = *(const float2*)(q + 128 + 2 * lane);
        float s = a.x + a.y + b.x + b.y;
        for (int off = 1; off < 64; off <<= 1) s += __shfl_xor(s, off);
        float mu = s * (1.0f / 256.0f);
        float d0 = a.x - mu, d1 = a.y - mu, d2 = b.x - mu, d3 = b.y - mu;
        float ss = d0 * d0 + d1 * d1 + d2 * d2 + d3 * d3;
        for (int off = 1; off < 64; off <<= 1) ss += __shfl_xor(ss, off);
        float rstd = rsqrtf(ss * (1.0f / 256.0f) + 1e-6f);
        int i0 = 2 * lane, i1 = 2 * lane + 128;
        float q0 = d0 * rstd * ln_w[i0]     + ln_b[i0];
        float q1 = d1 * rstd * ln_w[i0 + 1] + ln_b[i0 + 1];
        float q2 = d2 * rstd * ln_w[i1]     + ln_b[i1];
        float q3 = d3 * rstd * ln_w[i1 + 1] + ln_b[i1 + 1];
        *(uint32_t*)&U.qn[t * 264 + i0] = pk2(q0, q1);
        *(uint32_t*)&U.qn[t * 264 + i1] = pk2(q2, q3);
    }
    __syncthreads();

    // ---- step 2: h[16 tok][64] = qn @ w1^T + b1 (waves 0..3)
    if (wv < 4) {
        int nb = wv;
        f32x4 acc = {0.0f, 0.0f, 0.0f, 0.0f};
        for (int ks = 0; ks < 8; ++ks) {
            bf16x8 afr = *(const bf16x8*)&U.qn[ln16 * 264 + ks * 32 + lq * 8];
            bf16x8 bfr = *(const bf16x8*)&w1b[(nb * 16 + ln16) * 256 + ks * 32 + lq * 8];
            acc = __builtin_amdgcn_mfma_f32_16x16x32_bf16(afr, bfr, acc, 0, 0, 0);
        }
        float bias = b1[nb * 16 + ln16];
        for (int i = 0; i < 4; ++i) {
            int t = lq * 4 + i;                      // D row = token
            Hb[t * 64 + nb * 16 + ln16] = f2b(acc[i] + bias);
        }
    }
    __syncthreads();

    // ---- step 3: H B-frags; sm generation -> smT; x A-frag hoist
    bf16x8 hfr[2];
    hfr[0] = *(const bf16x8*)&Hb[ln16 * 64 + 0 + lq * 8];
    hfr[1] = *(const bf16x8*)&Hb[ln16 * 64 + 32 + lq * 8];

    for (int gi = 0; gi < 8; ++gi) {                 // sm rows 16384 + g*16 + m
        int g = wv * 8 + gi;
        int rbase = 16384 + g * 16;
        f32x4 acc = *(const f32x4*)&b2[rbase + lq * 4];
        for (int ks = 0; ks < 2; ++ks) {
            bf16x8 afr = *(const bf16x8*)&w2b[(size_t)(rbase + ln16) * 64 + ks * 32 + lq * 8];
            acc = __builtin_amdgcn_mfma_f32_16x16x32_bf16(afr, hfr[ks], acc, 0, 0, 0);
        }
        int o = g >> 1;
        int p0 = (g & 1) * 16 + lq * 4;
        uint2 wr;
        wr.x = pk2(acc[0], acc[1]);
        wr.y = pk2(acc[2], acc[3]);
        *(uint2*)&U.smT[ln16 * 1032 + o * 32 + p0] = wr;   // token-major, stride 1032
    }

    bf16x8 xa[2][2][4];                              // x A-frags [tt][p-half][ks]
    for (int tt = 0; tt < 2; ++tt) {
        const float* xp = sampled + (size_t)(tok0 + wv * 2 + tt) * 4096;
        for (int mt = 0; mt < 2; ++mt) {
            int p = mt * 16 + ln16;
            for (int ks = 0; ks < 4; ++ks) {
                int c = ks * 32 + lq * 8;
                float4 lo = *(const float4*)(xp + p * 128 + c);
                float4 hi = *(const float4*)(xp + p * 128 + c + 4);
                ushort8 u;
                u[0] = f2b(lo.x); u[1] = f2b(lo.y); u[2] = f2b(lo.z); u[3] = f2b(lo.w);
                u[4] = f2b(hi.x); u[5] = f2b(hi.y); u[6] = f2b(hi.z); u[7] = f2b(hi.w);
                xa[tt][mt][ks] = __builtin_bit_cast(bf16x8, u);
            }
        }
    }
    __syncthreads();

    // ---- step 4: sm A-frags (K=32) for this wave's 2 tokens
    bf16x8 sa[2][2];
    for (int tt = 0; tt < 2; ++tt) {
        int t = wv * 2 + tt;
        for (int mt = 0; mt < 2; ++mt)
            sa[tt][mt] = *(const bf16x8*)&U.smT[t * 1032 + (mt * 16 + ln16) * 32 + lq * 8];
    }
    __syncthreads();    // smT dead; pt/g1s alias it from here on

    // ---- main loop over 16 d-tiles of width 8; spatial every 2nd tile
    for (int dt = 0; dt < 16; ++dt) {
        // GEN: wave wv owns c-block cb=wv; P[c, token] for d = dt*8+dd
        const int cb = wv;
        for (int dd = 0; dd < 8; ++dd) {
            int d = dt * 8 + dd;
            int rb = cb * 2048 + d;                  // (cb*16)*128 + d
            f32x4 acc;
            acc[0] = b2[rb + (lq * 4 + 0) * 128];
            acc[1] = b2[rb + (lq * 4 + 1) * 128];
            acc[2] = b2[rb + (lq * 4 + 2) * 128];
            acc[3] = b2[rb + (lq * 4 + 3) * 128];
            for (int ks = 0; ks < 2; ++ks) {
                bf16x8 afr = *(const bf16x8*)&w2b[(size_t)(rb + ln16 * 128) * 64 + ks * 32 + lq * 8];
                acc = __builtin_amdgcn_mfma_f32_16x16x32_bf16(afr, hfr[ks], acc, 0, 0, 0);
            }
            // lane-linear pt: token=ln16, chunk=(c>>3)*8+dd, j=c&7; c=cb*16+lq*4+i
            uint2 wr;
            wr.x = pk2(acc[0], acc[1]);
            wr.y = pk2(acc[2], acc[3]);
            *(uint2*)&U.mp.pt[ln16 * 1032 + ((cb * 2 + (lq >> 1)) * 8 + dd) * 8 + (lq & 1) * 4] = wr;
        }
        __syncthreads();

        // CONSUME channel: 2 tokens per wave
        const int ddl = ln16 & 7;                    // lanes >=8 broadcast-duplicate
        for (int tt = 0; tt < 2; ++tt) {
            int t = wv * 2 + tt;
            bf16x8 bfr[4];
            for (int ks = 0; ks < 4; ++ks)
                bfr[ks] = *(const bf16x8*)&U.mp.pt[t * 1032 + (ks * 4 + lq) * 64 + ddl * 8];
            float mb = mb_s[dt * 8 + ddl];
            for (int mt = 0; mt < 2; ++mt) {
                f32x4 acc = {0.0f, 0.0f, 0.0f, 0.0f};
                for (int ks = 0; ks < 4; ++ks)
                    acc = __builtin_amdgcn_mfma_f32_16x16x32_bf16(xa[tt][mt][ks], bfr[ks], acc, 0, 0, 0);
                float g0 = gelu_fast(acc[0] + mb);
                float g1 = gelu_fast(acc[1] + mb);
                float g2 = gelu_fast(acc[2] + mb);
                float g3 = gelu_fast(acc[3] + mb);
                if (ln16 < 8) {
                    uint2 wr;
                    wr.x = pk2(g0, g1);
                    wr.y = pk2(g2, g3);
                    // g1s[t][d16][p], d16 = (dt&1)*8+ddl, row stride 40
                    *(uint2*)&U.mp.g1s[t * 640 + ((dt & 1) * 8 + ddl) * 40 + mt * 16 + lq * 4] = wr;
                }
            }
        }

        // SPATIAL on odd dt: full 16-lane n over paired d16 = 0..15
        if (dt & 1) {
            __builtin_amdgcn_wave_barrier();          // order same-wave LDS W->R
            int dt2 = dt >> 1;
            for (int tt = 0; tt < 2; ++tt) {
                int t = wv * 2 + tt;
                int tok = tok0 + t;
                bf16x8 gb = *(const bf16x8*)&U.mp.g1s[t * 640 + ln16 * 40 + lq * 8];
                for (int mt = 0; mt < 2; ++mt) {
                    f32x4 acc = {0.0f, 0.0f, 0.0f, 0.0f};
                    acc = __builtin_amdgcn_mfma_f32_16x16x32_bf16(sa[tt][mt], gb, acc, 0, 0, 0);
                    float4 sbv = *(const float4*)&sb_s[mt * 16 + lq * 4];
                    float g0 = gelu_fast(acc[0] + sbv.x);
                    float g1 = gelu_fast(acc[1] + sbv.y);
                    float g2 = gelu_fast(acc[2] + sbv.z);
                    float g3 = gelu_fast(acc[3] + sbv.w);
                    uint2 wr;
                    wr.x = pk2(g0, g1);
                    wr.y = pk2(g2, g3);
                    // y2 k'' = dt2*512 + d16*32 + o ; d16 = ln16, o = mt*16+lq*4+i
                    *(uint2*)&y2[(size_t)tok * 4096 + dt2 * 512 + ln16 * 32 + mt * 16 + lq * 4] = wr;
                }
            }
        }
        __syncthreads();
    }
}

// ---------------------------------------------------------------------------
// outproj: out[8192,256] = y2p[8192,4096] @ wob_p^T + bo. Full K, no atomics.
// 512 wgs x 256 thr; wg tile 32 tok x 128 q; wave tile 16 x 64.
__launch_bounds__(256, 4)
__global__ void outproj(const ushort* __restrict__ y2, const ushort* __restrict__ wob,
                        const float* __restrict__ bo, float* __restrict__ out) {
    int mb = blockIdx.x >> 1;            // 256 m-blocks of 32 tokens
    int nb = blockIdx.x & 1;             // 2 n-blocks of 128 q
    int tid = threadIdx.x;
    int wv = tid >> 6, lane = tid & 63, lq = lane >> 4, ln16 = lane & 15;
    int m0 = mb * 32 + (wv & 1) * 16;
    int n0 = nb * 128 + (wv >> 1) * 64;

    f32x4 acc[4];
    for (int nt = 0; nt < 4; ++nt) acc[nt] = (f32x4){0.0f, 0.0f, 0.0f, 0.0f};

    const ushort* arow = y2  + (size_t)(m0 + ln16) * 4096 + lq * 8;
    const ushort* brow = wob + (size_t)(n0 + ln16) * 4096 + lq * 8;
    #pragma unroll 2
    for (int kk = 0; kk < 4096; kk += 32) {
        bf16x8 af  = *(const bf16x8*)(arow + kk);
        bf16x8 b0  = *(const bf16x8*)(brow + kk);
        bf16x8 b1f = *(const bf16x8*)(brow + 16 * 4096 + kk);
        bf16x8 b2f = *(const bf16x8*)(brow + 32 * 4096 + kk);
        bf16x8 b3f = *(const bf16x8*)(brow + 48 * 4096 + kk);
        acc[0] = __builtin_amdgcn_mfma_f32_16x16x32_bf16(af, b0,  acc[0], 0, 0, 0);
        acc[1] = __builtin_amdgcn_mfma_f32_16x16x32_bf16(af, b1f, acc[1], 0, 0, 0);
        acc[2] = __builtin_amdgcn_mfma_f32_16x16x32_bf16(af, b2f, acc[2], 0, 0, 0);
        acc[3] = __builtin_amdgcn_mfma_f32_16x16x32_bf16(af, b3f, acc[3], 0, 0, 0);
    }
    for (int nt = 0; nt < 4; ++nt) {
        int q = n0 + nt * 16 + ln16;
        float bov = bo[q];
        for (int i = 0; i < 4; ++i) {
            int tok = m0 + lq * 4 + i;               // D row = token
            out[(size_t)tok * 256 + q] = acc[nt][i] + bov;
        }
    }
}

// ---------------------------------------------------------------------------
extern "C" void kernel_launch(void* const* d_in, const int* in_sizes, int n_in,
                              void* d_out, int out_size, void* d_ws, size_t ws_size,
                              hipStream_t stream) {
    const float* sampled = (const float*)d_in[0];
    const float* query   = (const float*)d_in[1];
    const float* ln_w    = (const float*)d_in[2];
    const float* ln_b    = (const float*)d_in[3];
    const float* w1      = (const float*)d_in[4];
    const float* b1      = (const float*)d_in[5];
    const float* w2      = (const float*)d_in[6];
    const float* b2      = (const float*)d_in[7];
    const float* m_beta  = (const float*)d_in[8];
    const float* s_beta  = (const float*)d_in[9];
    const float* wo      = (const float*)d_in[10];
    const float* bo      = (const float*)d_in[11];
    float* out = (float*)d_out;

    char* ws = (char*)d_ws;
    ushort* w2b = (ushort*)(ws);                    // 2,228,224 B
    ushort* wob = (ushort*)(ws + 2228224);          // 2,097,152 B (k''-permuted)
    ushort* w1b = (ushort*)(ws + 4325376);          //    32,768 B
    ushort* y2  = (ushort*)(ws + 4358144);          // 67,108,864 B (k'' layout)

    prep<<<4352, 256, 0, stream>>>(w2, w1, wo, w2b, w1b, wob);
    fused<<<512, 512, 0, stream>>>(sampled, query, ln_w, ln_b, b1, b2,
                                   m_beta, s_beta, w2b, w1b, y2);
    outproj<<<512, 256, 0, stream>>>(y2, wob, bo, out);
}

// Round 3
// 577.172 us; speedup vs baseline: 1.0386x; 1.0386x over previous
//
#include <hip/hip_runtime.h>
#include <cstdint>

// ---------------------------------------------------------------------------
// AdaptiveMixing fused kernel set, R3.
// R3 changes vs R2:
//  - fused: __launch_bounds__(512,2) (R2's (512,4) forced VGPR=64 -> scratch
//    spills: FETCH 88->268 MB. Never cap below the live-register budget.)
//  - prep: b2 channel bias transposed to b2t[d][c] -> GEN bias init is one
//    broadcast f32x4 load instead of 4 scalar strided loads
//  - outproj: 512 wgs x 512 thr; 8 waves split K (512 each), wave tile
//    16 tok x 256 q, LDS sequential reduction, coalesced fp32 stores.
//    16 waves/CU instead of 8; 17 loads per 16 MFMA.
// MFMA 16x16x32_bf16: A/B: idx lane&15, k=(lane>>4)*8+j; C/D: col=lane&15,
// row=(lane>>4)*4+i.
// ---------------------------------------------------------------------------

typedef __bf16 bf16x8 __attribute__((ext_vector_type(8)));
typedef float  f32x4  __attribute__((ext_vector_type(4)));
typedef unsigned short ushort;
typedef ushort ushort8 __attribute__((ext_vector_type(8)));

#define TW 16     // tokens per workgroup (fused)

__device__ __forceinline__ ushort f2b(float f) {
    union { float f; uint32_t u; } v; v.f = f;
    uint32_t u = v.u;
    u += 0x7fffu + ((u >> 16) & 1u);   // RNE
    return (ushort)(u >> 16);
}
__device__ __forceinline__ uint32_t pk2(float a, float b) {
    return (uint32_t)f2b(a) | ((uint32_t)f2b(b) << 16);
}
// Abramowitz-Stegun 7.1.26 erf (|err|<=1.5e-7), branchless; gelu exact form.
__device__ __forceinline__ float gelu_fast(float x) {
    float z = fabsf(x) * 0.70710678118654752440f;
    float t = __builtin_amdgcn_rcpf(fmaf(0.3275911f, z, 1.0f));
    float p = t * fmaf(t, fmaf(t, fmaf(t, fmaf(t, 1.061405429f, -1.453152027f),
                                       1.421413741f), -0.284496736f), 0.254829592f);
    float e = __expf(-z * z);
    float erfv = copysignf(fmaf(-p, e, 1.0f), x);
    return 0.5f * x * (1.0f + erfv);
}

// ---------------------------------------------------------------------------
// prep: bf16 copies of w1/w2; wo -> bf16 permuted to k'' order; b2t transpose.
// k'' = dt2*512 + d16*32 + o  <->  k = o*128 + dt2*16 + d16
__global__ void prep(const float* __restrict__ w2, const float* __restrict__ w1,
                     const float* __restrict__ wo, const float* __restrict__ b2,
                     ushort* __restrict__ w2b, ushort* __restrict__ w1b,
                     ushort* __restrict__ wob, float* __restrict__ b2t) {
    int i = blockIdx.x * 256 + threadIdx.x;          // 1,114,112 threads
    if (i < 1114112) w2b[i] = f2b(w2[i]);            // [17408][64]
    if (i < 16384)   w1b[i] = f2b(w1[i]);            // [64][256]
    if (i < 16384)   b2t[i] = b2[(i & 127) * 128 + (i >> 7)];  // [d][c]
    if (i < 1048576) {
        int q = i >> 12, r = i & 4095;
        int dt2 = r >> 9, d16 = (r >> 5) & 15, o = r & 31;
        wob[i] = f2b(wo[q * 4096 + o * 128 + dt2 * 16 + d16]);
    }
}

// ---------------------------------------------------------------------------
__launch_bounds__(512, 2)
__global__ void fused(const float* __restrict__ sampled, const float* __restrict__ query,
                      const float* __restrict__ ln_w, const float* __restrict__ ln_b,
                      const float* __restrict__ b1, const float* __restrict__ b2,
                      const float* __restrict__ m_beta, const float* __restrict__ s_beta,
                      const ushort* __restrict__ w2b, const ushort* __restrict__ w1b,
                      const float* __restrict__ b2t, ushort* __restrict__ y2) {
    __shared__ ushort Hb[TW * 64];                       // h bf16 [t][64]
    __shared__ union {
        ushort qn[TW * 264];                             // phase 1: LN out
        ushort smT[TW * 1032];                           // phase 2: sm [t][o*32+p]
        struct {
            ushort pt[TW * 1032];                        // [t][chunk(c>>3,dd)][c&7]
            ushort g1s[TW * 640];                        // [t][d16*40+p]
        } mp;                                            // main loop
    } U;
    __shared__ float mb_s[128];
    __shared__ float sb_s[32];

    const int tid  = threadIdx.x;
    const int wv   = tid >> 6;          // wave 0..7
    const int lane = tid & 63;
    const int lq   = lane >> 4;         // quad
    const int ln16 = lane & 15;
    const int tok0 = blockIdx.x * TW;

    if (tid < 128) mb_s[tid] = m_beta[tid];
    else if (tid < 160) sb_s[tid - 128] = s_beta[tid - 128];

    // ---- step 1: LayerNorm, 2 tokens per wave; qn -> LDS bf16 (row 264)
    for (int tt = 0; tt < 2; ++tt) {
        int t = wv * 2 + tt;
        const float* q = query + (size_t)(tok0 + t) * 256;
        float2 a = *(const float2*)(q + 2 * lane);
        float2 b = *(const float2*)(q + 128 + 2 * lane);
        float s = a.x + a.y + b.x + b.y;
        for (int off = 1; off < 64; off <<= 1) s += __shfl_xor(s, off);
        float mu = s * (1.0f / 256.0f);
        float d0 = a.x - mu, d1 = a.y - mu, d2 = b.x - mu, d3 = b.y - mu;
        float ss = d0 * d0 + d1 * d1 + d2 * d2 + d3 * d3;
        for (int off = 1; off < 64; off <<= 1) ss += __shfl_xor(ss, off);
        float rstd = rsqrtf(ss * (1.0f / 256.0f) + 1e-6f);
        int i0 = 2 * lane, i1 = 2 * lane + 128;
        float q0 = d0 * rstd * ln_w[i0]     + ln_b[i0];
        float q1 = d1 * rstd * ln_w[i0 + 1] + ln_b[i0 + 1];
        float q2 = d2 * rstd * ln_w[i1]     + ln_b[i1];
        float q3 = d3 * rstd * ln_w[i1 + 1] + ln_b[i1 + 1];
        *(uint32_t*)&U.qn[t * 264 + i0] = pk2(q0, q1);
        *(uint32_t*)&U.qn[t * 264 + i1] = pk2(q2, q3);
    }
    __syncthreads();

    // ---- step 2: h[16 tok][64] = qn @ w1^T + b1 (waves 0..3)
    if (wv < 4) {
        int nb = wv;
        f32x4 acc = {0.0f, 0.0f, 0.0f, 0.0f};
        for (int ks = 0; ks < 8; ++ks) {
            bf16x8 afr = *(const bf16x8*)&U.qn[ln16 * 264 + ks * 32 + lq * 8];
            bf16x8 bfr = *(const bf16x8*)&w1b[(nb * 16 + ln16) * 256 + ks * 32 + lq * 8];
            acc = __builtin_amdgcn_mfma_f32_16x16x32_bf16(afr, bfr, acc, 0, 0, 0);
        }
        float bias = b1[nb * 16 + ln16];
        for (int i = 0; i < 4; ++i) {
            int t = lq * 4 + i;                      // D row = token
            Hb[t * 64 + nb * 16 + ln16] = f2b(acc[i] + bias);
        }
    }
    __syncthreads();

    // ---- step 3: H B-frags; sm generation -> smT; x A-frag hoist
    bf16x8 hfr[2];
    hfr[0] = *(const bf16x8*)&Hb[ln16 * 64 + 0 + lq * 8];
    hfr[1] = *(const bf16x8*)&Hb[ln16 * 64 + 32 + lq * 8];

    for (int gi = 0; gi < 8; ++gi) {                 // sm rows 16384 + g*16 + m
        int g = wv * 8 + gi;
        int rbase = 16384 + g * 16;
        f32x4 acc = *(const f32x4*)&b2[rbase + lq * 4];
        for (int ks = 0; ks < 2; ++ks) {
            bf16x8 afr = *(const bf16x8*)&w2b[(size_t)(rbase + ln16) * 64 + ks * 32 + lq * 8];
            acc = __builtin_amdgcn_mfma_f32_16x16x32_bf16(afr, hfr[ks], acc, 0, 0, 0);
        }
        int o = g >> 1;
        int p0 = (g & 1) * 16 + lq * 4;
        uint2 wr;
        wr.x = pk2(acc[0], acc[1]);
        wr.y = pk2(acc[2], acc[3]);
        *(uint2*)&U.smT[ln16 * 1032 + o * 32 + p0] = wr;   // token-major, stride 1032
    }

    bf16x8 xa[2][2][4];                              // x A-frags [tt][p-half][ks]
    for (int tt = 0; tt < 2; ++tt) {
        const float* xp = sampled + (size_t)(tok0 + wv * 2 + tt) * 4096;
        for (int mt = 0; mt < 2; ++mt) {
            int p = mt * 16 + ln16;
            for (int ks = 0; ks < 4; ++ks) {
                int c = ks * 32 + lq * 8;
                float4 lo = *(const float4*)(xp + p * 128 + c);
                float4 hi = *(const float4*)(xp + p * 128 + c + 4);
                ushort8 u;
                u[0] = f2b(lo.x); u[1] = f2b(lo.y); u[2] = f2b(lo.z); u[3] = f2b(lo.w);
                u[4] = f2b(hi.x); u[5] = f2b(hi.y); u[6] = f2b(hi.z); u[7] = f2b(hi.w);
                xa[tt][mt][ks] = __builtin_bit_cast(bf16x8, u);
            }
        }
    }
    __syncthreads();

    // ---- step 4: sm A-frags (K=32) for this wave's 2 tokens
    bf16x8 sa[2][2];
    for (int tt = 0; tt < 2; ++tt) {
        int t = wv * 2 + tt;
        for (int mt = 0; mt < 2; ++mt)
            sa[tt][mt] = *(const bf16x8*)&U.smT[t * 1032 + (mt * 16 + ln16) * 32 + lq * 8];
    }
    __syncthreads();    // smT dead; pt/g1s alias it from here on

    // ---- main loop over 16 d-tiles of width 8; spatial every 2nd tile
    for (int dt = 0; dt < 16; ++dt) {
        // GEN: wave wv owns c-block cb=wv; P[c, token] for d = dt*8+dd
        const int cb = wv;
        for (int dd = 0; dd < 8; ++dd) {
            int d = dt * 8 + dd;
            int rb = cb * 2048 + d;                  // (cb*16)*128 + d
            // bias: b2t[d][c], c = cb*16 + lq*4 + i -> one broadcast f32x4
            f32x4 acc = *(const f32x4*)&b2t[d * 128 + cb * 16 + lq * 4];
            for (int ks = 0; ks < 2; ++ks) {
                bf16x8 afr = *(const bf16x8*)&w2b[(size_t)(rb + ln16 * 128) * 64 + ks * 32 + lq * 8];
                acc = __builtin_amdgcn_mfma_f32_16x16x32_bf16(afr, hfr[ks], acc, 0, 0, 0);
            }
            // lane-linear pt: token=ln16, chunk=(c>>3)*8+dd, j=c&7; c=cb*16+lq*4+i
            uint2 wr;
            wr.x = pk2(acc[0], acc[1]);
            wr.y = pk2(acc[2], acc[3]);
            *(uint2*)&U.mp.pt[ln16 * 1032 + ((cb * 2 + (lq >> 1)) * 8 + dd) * 8 + (lq & 1) * 4] = wr;
        }
        __syncthreads();

        // CONSUME channel: 2 tokens per wave
        const int ddl = ln16 & 7;                    // lanes >=8 broadcast-duplicate
        for (int tt = 0; tt < 2; ++tt) {
            int t = wv * 2 + tt;
            bf16x8 bfr[4];
            for (int ks = 0; ks < 4; ++ks)
                bfr[ks] = *(const bf16x8*)&U.mp.pt[t * 1032 + (ks * 4 + lq) * 64 + ddl * 8];
            float mb = mb_s[dt * 8 + ddl];
            for (int mt = 0; mt < 2; ++mt) {
                f32x4 acc = {0.0f, 0.0f, 0.0f, 0.0f};
                for (int ks = 0; ks < 4; ++ks)
                    acc = __builtin_amdgcn_mfma_f32_16x16x32_bf16(xa[tt][mt][ks], bfr[ks], acc, 0, 0, 0);
                float g0 = gelu_fast(acc[0] + mb);
                float g1 = gelu_fast(acc[1] + mb);
                float g2 = gelu_fast(acc[2] + mb);
                float g3 = gelu_fast(acc[3] + mb);
                if (ln16 < 8) {
                    uint2 wr;
                    wr.x = pk2(g0, g1);
                    wr.y = pk2(g2, g3);
                    // g1s[t][d16][p], d16 = (dt&1)*8+ddl, row stride 40
                    *(uint2*)&U.mp.g1s[t * 640 + ((dt & 1) * 8 + ddl) * 40 + mt * 16 + lq * 4] = wr;
                }
            }
        }

        // SPATIAL on odd dt: full 16-lane n over paired d16 = 0..15
        if (dt & 1) {
            __builtin_amdgcn_wave_barrier();          // order same-wave LDS W->R
            int dt2 = dt >> 1;
            for (int tt = 0; tt < 2; ++tt) {
                int t = wv * 2 + tt;
                int tok = tok0 + t;
                bf16x8 gb = *(const bf16x8*)&U.mp.g1s[t * 640 + ln16 * 40 + lq * 8];
                for (int mt = 0; mt < 2; ++mt) {
                    f32x4 acc = {0.0f, 0.0f, 0.0f, 0.0f};
                    acc = __builtin_amdgcn_mfma_f32_16x16x32_bf16(sa[tt][mt], gb, acc, 0, 0, 0);
                    float4 sbv = *(const float4*)&sb_s[mt * 16 + lq * 4];
                    float g0 = gelu_fast(acc[0] + sbv.x);
                    float g1 = gelu_fast(acc[1] + sbv.y);
                    float g2 = gelu_fast(acc[2] + sbv.z);
                    float g3 = gelu_fast(acc[3] + sbv.w);
                    uint2 wr;
                    wr.x = pk2(g0, g1);
                    wr.y = pk2(g2, g3);
                    // y2 k'' = dt2*512 + d16*32 + o ; d16 = ln16, o = mt*16+lq*4+i
                    *(uint2*)&y2[(size_t)tok * 4096 + dt2 * 512 + ln16 * 32 + mt * 16 + lq * 4] = wr;
                }
            }
        }
        __syncthreads();
    }
}

// ---------------------------------------------------------------------------
// outproj: out[8192,256] = y2p[8192,4096] @ wob_p^T + bo.
// 512 wgs x 512 thr; wg owns 16 tokens x 256 q; 8 waves split K (512 each);
// LDS sequential reduction; coalesced fp32 stores. No atomics.
__launch_bounds__(512, 2)
__global__ void outproj(const ushort* __restrict__ y2, const ushort* __restrict__ wob,
                        const float* __restrict__ bo, float* __restrict__ out) {
    __shared__ float red[16 * 264];
    const int tid  = threadIdx.x;
    const int wv   = tid >> 6;
    const int lane = tid & 63;
    const int lq   = lane >> 4;
    const int ln16 = lane & 15;
    const int tok0 = blockIdx.x * 16;
    const int kc   = wv * 512;                      // this wave's K-chunk

    f32x4 acc[16];
    for (int nt = 0; nt < 16; ++nt) acc[nt] = (f32x4){0.0f, 0.0f, 0.0f, 0.0f};

    const ushort* ap = y2  + (size_t)(tok0 + ln16) * 4096 + kc + lq * 8;
    const ushort* bp = wob + (size_t)ln16 * 4096 + kc + lq * 8;
    #pragma unroll 2
    for (int it = 0; it < 16; ++it) {
        int kk = it * 32;
        bf16x8 af = *(const bf16x8*)(ap + kk);
        for (int nh = 0; nh < 2; ++nh) {
            bf16x8 bf[8];
            for (int j = 0; j < 8; ++j)
                bf[j] = *(const bf16x8*)(bp + (size_t)(nh * 8 + j) * 16 * 4096 + kk);
            for (int j = 0; j < 8; ++j)
                acc[nh * 8 + j] = __builtin_amdgcn_mfma_f32_16x16x32_bf16(af, bf[j], acc[nh * 8 + j], 0, 0, 0);
        }
    }

    // sequential cross-wave reduction in LDS
    for (int w = 0; w < 8; ++w) {
        if (wv == w) {
            for (int nt = 0; nt < 16; ++nt)
                for (int i = 0; i < 4; ++i) {
                    float* p = &red[(lq * 4 + i) * 264 + nt * 16 + ln16];
                    if (w == 0) *p = acc[nt][i];
                    else        *p += acc[nt][i];
                }
        }
        __syncthreads();
    }

    // coalesced store: thread -> (row r, 8 q)
    int r  = tid >> 5;
    int q0 = (tid & 31) * 8;
    float4 a0 = *(const float4*)&red[r * 264 + q0];
    float4 a1 = *(const float4*)&red[r * 264 + q0 + 4];
    float4 b0 = *(const float4*)&bo[q0];
    float4 b1 = *(const float4*)&bo[q0 + 4];
    float4 o0 = {a0.x + b0.x, a0.y + b0.y, a0.z + b0.z, a0.w + b0.w};
    float4 o1 = {a1.x + b1.x, a1.y + b1.y, a1.z + b1.z, a1.w + b1.w};
    float* op = out + (size_t)(tok0 + r) * 256 + q0;
    *(float4*)op = o0;
    *(float4*)(op + 4) = o1;
}

// ---------------------------------------------------------------------------
extern "C" void kernel_launch(void* const* d_in, const int* in_sizes, int n_in,
                              void* d_out, int out_size, void* d_ws, size_t ws_size,
                              hipStream_t stream) {
    const float* sampled = (const float*)d_in[0];
    const float* query   = (const float*)d_in[1];
    const float* ln_w    = (const float*)d_in[2];
    const float* ln_b    = (const float*)d_in[3];
    const float* w1      = (const float*)d_in[4];
    const float* b1      = (const float*)d_in[5];
    const float* w2      = (const float*)d_in[6];
    const float* b2      = (const float*)d_in[7];
    const float* m_beta  = (const float*)d_in[8];
    const float* s_beta  = (const float*)d_in[9];
    const float* wo      = (const float*)d_in[10];
    const float* bo      = (const float*)d_in[11];
    float* out = (float*)d_out;

    char* ws = (char*)d_ws;
    ushort* w2b = (ushort*)(ws);                    // 2,228,224 B
    ushort* wob = (ushort*)(ws + 2228224);          // 2,097,152 B (k''-permuted)
    ushort* w1b = (ushort*)(ws + 4325376);          //    32,768 B
    ushort* y2  = (ushort*)(ws + 4358144);          // 67,108,864 B (k'' layout)
    float*  b2t = (float*)(ws + 71467008);          //    65,536 B (total ~68.2 MB)

    prep<<<4352, 256, 0, stream>>>(w2, w1, wo, b2, w2b, w1b, wob, b2t);
    fused<<<512, 512, 0, stream>>>(sampled, query, ln_w, ln_b, b1, b2,
                                   m_beta, s_beta, w2b, w1b, b2t, y2);
    outproj<<<512, 512, 0, stream>>>(y2, wob, bo, out);
}

// Round 4
// 450.764 us; speedup vs baseline: 1.3298x; 1.2804x over previous
//
#include <hip/hip_runtime.h>
#include <cstdint>

// ---------------------------------------------------------------------------
// AdaptiveMixing fused kernel set, R4.
// R4 theme: kill 64-line divergent gathers. All hot global loads become
// lane-linear (fragment-major) via prep-time permutes:
//   w2p  [cb][d][ks][lane][8]   channel-gen A-frags   (coalesced 1KB loads)
//   w2sp [g][ks][lane][8]       sm-gen A-frags
//   w1p  [nb][ks][lane][8]      h-gen B-frags
//   wop  [kc5][nb][lane][8]     outproj B-frags
//   y2f  [tb16][kc5][lane][8]   outproj A-frags -- written by fused directly
// outproj: 256 blocks x 32 tokens (halves wob L2 traffic), 8-wave K-split,
// LDS sequential reduction, no atomics.
// MFMA 16x16x32_bf16: A/B: idx lane&15, k=(lane>>4)*8+j; C/D: col=lane&15,
// row=(lane>>4)*4+i.
// ---------------------------------------------------------------------------

typedef __bf16 bf16x8 __attribute__((ext_vector_type(8)));
typedef float  f32x4  __attribute__((ext_vector_type(4)));
typedef unsigned short ushort;
typedef ushort ushort8 __attribute__((ext_vector_type(8)));

#define TW 16     // tokens per fused workgroup

__device__ __forceinline__ ushort f2b(float f) {
    union { float f; uint32_t u; } v; v.f = f;
    uint32_t u = v.u;
    u += 0x7fffu + ((u >> 16) & 1u);   // RNE
    return (ushort)(u >> 16);
}
__device__ __forceinline__ uint32_t pk2(float a, float b) {
    return (uint32_t)f2b(a) | ((uint32_t)f2b(b) << 16);
}
// Abramowitz-Stegun 7.1.26 erf (|err|<=1.5e-7), branchless; gelu exact form.
__device__ __forceinline__ float gelu_fast(float x) {
    float z = fabsf(x) * 0.70710678118654752440f;
    float t = __builtin_amdgcn_rcpf(fmaf(0.3275911f, z, 1.0f));
    float p = t * fmaf(t, fmaf(t, fmaf(t, fmaf(t, 1.061405429f, -1.453152027f),
                                       1.421413741f), -0.284496736f), 0.254829592f);
    float e = __expf(-z * z);
    float erfv = copysignf(fmaf(-p, e, 1.0f), x);
    return 0.5f * x * (1.0f + erfv);
}

// ---------------------------------------------------------------------------
// prep: fragment-linear bf16 permutes. 4096 x 256 threads.
__global__ void prep(const float* __restrict__ w2, const float* __restrict__ w1,
                     const float* __restrict__ wo, const float* __restrict__ b2,
                     ushort* __restrict__ w2p, ushort* __restrict__ w2sp,
                     ushort* __restrict__ w1p, ushort* __restrict__ wop,
                     float* __restrict__ b2t) {
    int i = blockIdx.x * 256 + threadIdx.x;          // 1,048,576 threads
    {   // w2p: channel rows 0..16383. i = cb<<17 | d<<10 | ks<<9 | l<<3 | j
        int j = i & 7, l = (i >> 3) & 63, ks = (i >> 9) & 1;
        int d = (i >> 10) & 127, cb = (i >> 17) & 7;
        w2p[i] = f2b(w2[(size_t)((cb * 16 + (l & 15)) * 128 + d) * 64 +
                        ks * 32 + (l >> 4) * 8 + j]);
    }
    {   // wop: i = kc5<<13 | nb<<9 | l<<3 | j ; k'' = kc5*32 + (l>>4)*8 + j
        int j = i & 7, l = (i >> 3) & 63, nb = (i >> 9) & 15, kc5 = (i >> 13) & 127;
        int o = (l >> 4) * 8 + j, q = nb * 16 + (l & 15);
        int d16 = kc5 & 15, dt2 = kc5 >> 4;
        wop[i] = f2b(wo[(size_t)q * 4096 + o * 128 + dt2 * 16 + d16]);
    }
    if (i < 65536) {  // w2sp: sm rows 16384..17407. i = g<<10 | ks<<9 | l<<3 | j
        int j = i & 7, l = (i >> 3) & 63, ks = (i >> 9) & 1, g = (i >> 10) & 63;
        w2sp[i] = f2b(w2[(size_t)(16384 + g * 16 + (l & 15)) * 64 +
                         ks * 32 + (l >> 4) * 8 + j]);
    }
    if (i < 16384) {  // w1p: i = nb<<12 | ks<<9 | l<<3 | j
        int j = i & 7, l = (i >> 3) & 63, ks = (i >> 9) & 7, nb = i >> 12;
        w1p[i] = f2b(w1[(nb * 16 + (l & 15)) * 256 + ks * 32 + (l >> 4) * 8 + j]);
        b2t[i] = b2[(i & 127) * 128 + (i >> 7)];      // [d][c]
    }
}

// ---------------------------------------------------------------------------
__launch_bounds__(512, 2)
__global__ void fused(const float* __restrict__ sampled, const float* __restrict__ query,
                      const float* __restrict__ ln_w, const float* __restrict__ ln_b,
                      const float* __restrict__ b1, const float* __restrict__ b2,
                      const float* __restrict__ m_beta, const float* __restrict__ s_beta,
                      const ushort* __restrict__ w2p, const ushort* __restrict__ w2sp,
                      const ushort* __restrict__ w1p, const float* __restrict__ b2t,
                      ushort* __restrict__ y2f) {
    __shared__ ushort Hb[TW * 64];                       // h bf16 [t][64]
    __shared__ union {
        ushort qn[TW * 264];                             // phase 1: LN out
        ushort smT[TW * 1032];                           // phase 2: sm [t][o*32+p]
        struct {
            ushort pt[TW * 1032];                        // [t][chunk(c>>3,dd)][c&7]
            ushort g1s[TW * 640];                        // [t][d16*40+p]
        } mp;                                            // main loop
    } U;
    __shared__ float mb_s[128];
    __shared__ float sb_s[32];

    const int tid  = threadIdx.x;
    const int wv   = tid >> 6;          // wave 0..7
    const int lane = tid & 63;
    const int lq   = lane >> 4;         // quad
    const int ln16 = lane & 15;
    const int tok0 = blockIdx.x * TW;

    if (tid < 128) mb_s[tid] = m_beta[tid];
    else if (tid < 160) sb_s[tid - 128] = s_beta[tid - 128];

    // ---- step 1: LayerNorm, 2 tokens per wave; qn -> LDS bf16 (row 264)
    for (int tt = 0; tt < 2; ++tt) {
        int t = wv * 2 + tt;
        const float* q = query + (size_t)(tok0 + t) * 256;
        float2 a = *(const float2*)(q + 2 * lane);
        float2 b = *(const float2*)(q + 128 + 2 * lane);
        float s = a.x + a.y + b.x + b.y;
        for (int off = 1; off < 64; off <<= 1) s += __shfl_xor(s, off);
        float mu = s * (1.0f / 256.0f);
        float d0 = a.x - mu, d1 = a.y - mu, d2 = b.x - mu, d3 = b.y - mu;
        float ss = d0 * d0 + d1 * d1 + d2 * d2 + d3 * d3;
        for (int off = 1; off < 64; off <<= 1) ss += __shfl_xor(ss, off);
        float rstd = rsqrtf(ss * (1.0f / 256.0f) + 1e-6f);
        int i0 = 2 * lane, i1 = 2 * lane + 128;
        float q0 = d0 * rstd * ln_w[i0]     + ln_b[i0];
        float q1 = d1 * rstd * ln_w[i0 + 1] + ln_b[i0 + 1];
        float q2 = d2 * rstd * ln_w[i1]     + ln_b[i1];
        float q3 = d3 * rstd * ln_w[i1 + 1] + ln_b[i1 + 1];
        *(uint32_t*)&U.qn[t * 264 + i0] = pk2(q0, q1);
        *(uint32_t*)&U.qn[t * 264 + i1] = pk2(q2, q3);
    }
    __syncthreads();

    // ---- step 2: h[16 tok][64] = qn @ w1^T + b1 (waves 0..3)
    if (wv < 4) {
        int nb = wv;
        f32x4 acc = {0.0f, 0.0f, 0.0f, 0.0f};
        for (int ks = 0; ks < 8; ++ks) {
            bf16x8 afr = *(const bf16x8*)&U.qn[ln16 * 264 + ks * 32 + lq * 8];
            bf16x8 bfr = *(const bf16x8*)&w1p[(nb * 8 + ks) * 512 + lane * 8];
            acc = __builtin_amdgcn_mfma_f32_16x16x32_bf16(afr, bfr, acc, 0, 0, 0);
        }
        float bias = b1[nb * 16 + ln16];
        for (int i = 0; i < 4; ++i) {
            int t = lq * 4 + i;                      // D row = token
            Hb[t * 64 + nb * 16 + ln16] = f2b(acc[i] + bias);
        }
    }
    __syncthreads();

    // ---- step 3: H B-frags; sm generation -> smT; x A-frag hoist
    bf16x8 hfr[2];
    hfr[0] = *(const bf16x8*)&Hb[ln16 * 64 + 0 + lq * 8];
    hfr[1] = *(const bf16x8*)&Hb[ln16 * 64 + 32 + lq * 8];

    for (int gi = 0; gi < 8; ++gi) {                 // sm rows 16384 + g*16 + m
        int g = wv * 8 + gi;
        f32x4 acc = *(const f32x4*)&b2[16384 + g * 16 + lq * 4];
        for (int ks = 0; ks < 2; ++ks) {
            bf16x8 afr = *(const bf16x8*)&w2sp[(g * 2 + ks) * 512 + lane * 8];
            acc = __builtin_amdgcn_mfma_f32_16x16x32_bf16(afr, hfr[ks], acc, 0, 0, 0);
        }
        int o = g >> 1;
        int p0 = (g & 1) * 16 + lq * 4;
        uint2 wr;
        wr.x = pk2(acc[0], acc[1]);
        wr.y = pk2(acc[2], acc[3]);
        *(uint2*)&U.smT[ln16 * 1032 + o * 32 + p0] = wr;   // token-major
    }

    bf16x8 xa[2][2][4];                              // x A-frags [tt][p-half][ks]
    for (int tt = 0; tt < 2; ++tt) {
        const float* xp = sampled + (size_t)(tok0 + wv * 2 + tt) * 4096;
        for (int mt = 0; mt < 2; ++mt) {
            int p = mt * 16 + ln16;
            for (int ks = 0; ks < 4; ++ks) {
                int c = ks * 32 + lq * 8;
                float4 lo = *(const float4*)(xp + p * 128 + c);
                float4 hi = *(const float4*)(xp + p * 128 + c + 4);
                ushort8 u;
                u[0] = f2b(lo.x); u[1] = f2b(lo.y); u[2] = f2b(lo.z); u[3] = f2b(lo.w);
                u[4] = f2b(hi.x); u[5] = f2b(hi.y); u[6] = f2b(hi.z); u[7] = f2b(hi.w);
                xa[tt][mt][ks] = __builtin_bit_cast(bf16x8, u);
            }
        }
    }
    __syncthreads();

    // ---- step 4: sm A-frags (K=32) for this wave's 2 tokens
    bf16x8 sa[2][2];
    for (int tt = 0; tt < 2; ++tt) {
        int t = wv * 2 + tt;
        for (int mt = 0; mt < 2; ++mt)
            sa[tt][mt] = *(const bf16x8*)&U.smT[t * 1032 + (mt * 16 + ln16) * 32 + lq * 8];
    }
    __syncthreads();    // smT dead; pt/g1s alias it from here on

    // ---- main loop over 16 d-tiles of width 8; spatial every 2nd tile
    for (int dt = 0; dt < 16; ++dt) {
        // GEN: wave wv owns c-block cb=wv; P[c, token] for d = dt*8+dd
        const int cb = wv;
        for (int dd = 0; dd < 8; ++dd) {
            int d = dt * 8 + dd;
            // bias: b2t[d][c], c = cb*16 + lq*4 + i -> one broadcast f32x4
            f32x4 acc = *(const f32x4*)&b2t[d * 128 + cb * 16 + lq * 4];
            for (int ks = 0; ks < 2; ++ks) {
                bf16x8 afr = *(const bf16x8*)&w2p[((cb * 128 + d) * 2 + ks) * 512 + lane * 8];
                acc = __builtin_amdgcn_mfma_f32_16x16x32_bf16(afr, hfr[ks], acc, 0, 0, 0);
            }
            // lane-linear pt: token=ln16, chunk=(c>>3)*8+dd, j=c&7
            uint2 wr;
            wr.x = pk2(acc[0], acc[1]);
            wr.y = pk2(acc[2], acc[3]);
            *(uint2*)&U.mp.pt[ln16 * 1032 + ((cb * 2 + (lq >> 1)) * 8 + dd) * 8 + (lq & 1) * 4] = wr;
        }
        __syncthreads();

        // CONSUME channel: 2 tokens per wave
        const int ddl = ln16 & 7;                    // lanes >=8 broadcast-duplicate
        for (int tt = 0; tt < 2; ++tt) {
            int t = wv * 2 + tt;
            bf16x8 bfr[4];
            for (int ks = 0; ks < 4; ++ks)
                bfr[ks] = *(const bf16x8*)&U.mp.pt[t * 1032 + (ks * 4 + lq) * 64 + ddl * 8];
            float mb = mb_s[dt * 8 + ddl];
            for (int mt = 0; mt < 2; ++mt) {
                f32x4 acc = {0.0f, 0.0f, 0.0f, 0.0f};
                for (int ks = 0; ks < 4; ++ks)
                    acc = __builtin_amdgcn_mfma_f32_16x16x32_bf16(xa[tt][mt][ks], bfr[ks], acc, 0, 0, 0);
                float g0 = gelu_fast(acc[0] + mb);
                float g1 = gelu_fast(acc[1] + mb);
                float g2 = gelu_fast(acc[2] + mb);
                float g3 = gelu_fast(acc[3] + mb);
                if (ln16 < 8) {
                    uint2 wr;
                    wr.x = pk2(g0, g1);
                    wr.y = pk2(g2, g3);
                    // g1s[t][d16][p], d16 = (dt&1)*8+ddl, row stride 40
                    *(uint2*)&U.mp.g1s[t * 640 + ((dt & 1) * 8 + ddl) * 40 + mt * 16 + lq * 4] = wr;
                }
            }
        }

        // SPATIAL on odd dt: full 16-lane n over paired d16 = 0..15
        if (dt & 1) {
            __builtin_amdgcn_wave_barrier();          // order same-wave LDS W->R
            int dt2 = dt >> 1;
            for (int tt = 0; tt < 2; ++tt) {
                int t = wv * 2 + tt;
                bf16x8 gb = *(const bf16x8*)&U.mp.g1s[t * 640 + ln16 * 40 + lq * 8];
                for (int mt = 0; mt < 2; ++mt) {
                    f32x4 acc = {0.0f, 0.0f, 0.0f, 0.0f};
                    acc = __builtin_amdgcn_mfma_f32_16x16x32_bf16(sa[tt][mt], gb, acc, 0, 0, 0);
                    float4 sbv = *(const float4*)&sb_s[mt * 16 + lq * 4];
                    float g0 = gelu_fast(acc[0] + sbv.x);
                    float g1 = gelu_fast(acc[1] + sbv.y);
                    float g2 = gelu_fast(acc[2] + sbv.z);
                    float g3 = gelu_fast(acc[3] + sbv.w);
                    uint2 wr;
                    wr.x = pk2(g0, g1);
                    wr.y = pk2(g2, g3);
                    // y2f A-frag-linear: kc5 = dt2*16 + d16(=ln16),
                    // l = t + (o>>3)*16, j = o&7; o = mt*16 + lq*4 + i
                    size_t addr = (size_t)blockIdx.x * 65536 +
                                  (dt2 * 16 + ln16) * 512 +
                                  (t + (mt * 2 + (lq >> 1)) * 16) * 8 + (lq & 1) * 4;
                    *(uint2*)&y2f[addr] = wr;
                }
            }
        }
        __syncthreads();
    }
}

// ---------------------------------------------------------------------------
// outproj: out[8192,256] = y2 @ wo^T + bo in fragment-linear space.
// 256 blocks x 512 thr; block = 32 tokens (2 fused tbs) x 256 q; 8 waves
// split K (512 each); LDS sequential reduction; coalesced fp32 stores.
__launch_bounds__(512, 2)
__global__ void outproj(const ushort* __restrict__ y2f, const ushort* __restrict__ wop,
                        const float* __restrict__ bo, float* __restrict__ out) {
    __shared__ float red[32 * 264];
    const int tid  = threadIdx.x;
    const int wv   = tid >> 6;
    const int lane = tid & 63;
    const int lq   = lane >> 4;
    const int ln16 = lane & 15;
    const int tb   = blockIdx.x;                     // 32-token block

    f32x4 acc[2][16];
    for (int m = 0; m < 2; ++m)
        for (int nb = 0; nb < 16; ++nb) acc[m][nb] = (f32x4){0.0f, 0.0f, 0.0f, 0.0f};

    const ushort* ap0 = y2f + ((size_t)(tb * 2 + 0) * 128 + wv * 16) * 512 + lane * 8;
    const ushort* ap1 = y2f + ((size_t)(tb * 2 + 1) * 128 + wv * 16) * 512 + lane * 8;
    const ushort* bp  = wop + (size_t)(wv * 16) * 8192 + lane * 8;
    for (int it = 0; it < 16; ++it) {
        bf16x8 a0 = *(const bf16x8*)(ap0 + it * 512);
        bf16x8 a1 = *(const bf16x8*)(ap1 + it * 512);
        for (int nb = 0; nb < 16; ++nb) {
            bf16x8 bf = *(const bf16x8*)(bp + (it * 16 + nb) * 512);
            acc[0][nb] = __builtin_amdgcn_mfma_f32_16x16x32_bf16(a0, bf, acc[0][nb], 0, 0, 0);
            acc[1][nb] = __builtin_amdgcn_mfma_f32_16x16x32_bf16(a1, bf, acc[1][nb], 0, 0, 0);
        }
    }

    // sequential cross-wave reduction in LDS; row = m*16 + lq*4 + i
    for (int w = 0; w < 8; ++w) {
        if (wv == w) {
            for (int m = 0; m < 2; ++m)
                for (int nb = 0; nb < 16; ++nb)
                    for (int i = 0; i < 4; ++i) {
                        float* p = &red[(m * 16 + lq * 4 + i) * 264 + nb * 16 + ln16];
                        if (w == 0) *p = acc[m][nb][i];
                        else        *p += acc[m][nb][i];
                    }
        }
        __syncthreads();
    }

    // coalesced store: thread -> (row r, 16 q)
    int r  = tid >> 4;
    int q0 = (tid & 15) * 16;
    float* op = out + (size_t)(tb * 32 + r) * 256 + q0;
    for (int c = 0; c < 16; c += 4) {
        float4 a = *(const float4*)&red[r * 264 + q0 + c];
        float4 b = *(const float4*)&bo[q0 + c];
        float4 o = {a.x + b.x, a.y + b.y, a.z + b.z, a.w + b.w};
        *(float4*)(op + c) = o;
    }
}

// ---------------------------------------------------------------------------
extern "C" void kernel_launch(void* const* d_in, const int* in_sizes, int n_in,
                              void* d_out, int out_size, void* d_ws, size_t ws_size,
                              hipStream_t stream) {
    const float* sampled = (const float*)d_in[0];
    const float* query   = (const float*)d_in[1];
    const float* ln_w    = (const float*)d_in[2];
    const float* ln_b    = (const float*)d_in[3];
    const float* w1      = (const float*)d_in[4];
    const float* b1      = (const float*)d_in[5];
    const float* w2      = (const float*)d_in[6];
    const float* b2      = (const float*)d_in[7];
    const float* m_beta  = (const float*)d_in[8];
    const float* s_beta  = (const float*)d_in[9];
    const float* wo      = (const float*)d_in[10];
    const float* bo      = (const float*)d_in[11];
    float* out = (float*)d_out;

    char* ws = (char*)d_ws;
    ushort* w2p  = (ushort*)(ws);                   // 2,097,152 B
    ushort* wop  = (ushort*)(ws + 2097152);         // 2,097,152 B
    ushort* w2sp = (ushort*)(ws + 4194304);         //   131,072 B
    ushort* w1p  = (ushort*)(ws + 4325376);         //    32,768 B
    float*  b2t  = (float*) (ws + 4358144);         //    65,536 B
    ushort* y2f  = (ushort*)(ws + 4423680);         // 67,108,864 B (total ~68.2 MB)

    prep<<<4096, 256, 0, stream>>>(w2, w1, wo, b2, w2p, w2sp, w1p, wop, b2t);
    fused<<<512, 512, 0, stream>>>(sampled, query, ln_w, ln_b, b1, b2,
                                   m_beta, s_beta, w2p, w2sp, w1p, b2t, y2f);
    outproj<<<256, 512, 0, stream>>>(y2f, wop, bo, out);
}

// Round 5
// 387.687 us; speedup vs baseline: 1.5462x; 1.1627x over previous
//
#include <hip/hip_runtime.h>
#include <cstdint>

// ---------------------------------------------------------------------------
// AdaptiveMixing fused kernel set, R5.
// R5 changes vs R4:
//  - outproj rewritten spill-free: 256 blocks x 512 thr, wave = 32 tok x 32 q
//    over FULL K (128 kc5 steps). acc[2][2] = 16 VGPRs (R4 had 128 VGPRs of
//    acc under a 128-VGPR cap -> spills). No LDS reduction, no atomics,
//    direct coalesced stores. 4 loads : 4 MFMA per k-step, all lane-linear.
//  - fused CONSUME: branchless gelu de-dup. Lanes n>=8 hold a duplicate of
//    lanes n-8's MFMA acc; select rows {0,1} vs {2,3} by lane half via
//    cndmask, compute 2 gelu/lane instead of 4, store 4B per lane.
//    (NOT an if/else -- divergent halves would serialize and save nothing.)
// Layouts (from R4):
//   w2p  [cb][d][ks][lane][8], w2sp [g][ks][lane][8], w1p [nb][ks][lane][8],
//   wop  [kc5][nb][lane][8],   y2f  [tb16][kc5][lane][8]
// MFMA 16x16x32_bf16: A/B: idx lane&15, k=(lane>>4)*8+j; C/D: col=lane&15,
// row=(lane>>4)*4+i.
// ---------------------------------------------------------------------------

typedef __bf16 bf16x8 __attribute__((ext_vector_type(8)));
typedef float  f32x4  __attribute__((ext_vector_type(4)));
typedef unsigned short ushort;
typedef ushort ushort8 __attribute__((ext_vector_type(8)));

#define TW 16     // tokens per fused workgroup

__device__ __forceinline__ ushort f2b(float f) {
    union { float f; uint32_t u; } v; v.f = f;
    uint32_t u = v.u;
    u += 0x7fffu + ((u >> 16) & 1u);   // RNE
    return (ushort)(u >> 16);
}
__device__ __forceinline__ uint32_t pk2(float a, float b) {
    return (uint32_t)f2b(a) | ((uint32_t)f2b(b) << 16);
}
// Abramowitz-Stegun 7.1.26 erf (|err|<=1.5e-7), branchless; gelu exact form.
__device__ __forceinline__ float gelu_fast(float x) {
    float z = fabsf(x) * 0.70710678118654752440f;
    float t = __builtin_amdgcn_rcpf(fmaf(0.3275911f, z, 1.0f));
    float p = t * fmaf(t, fmaf(t, fmaf(t, fmaf(t, 1.061405429f, -1.453152027f),
                                       1.421413741f), -0.284496736f), 0.254829592f);
    float e = __expf(-z * z);
    float erfv = copysignf(fmaf(-p, e, 1.0f), x);
    return 0.5f * x * (1.0f + erfv);
}

// ---------------------------------------------------------------------------
// prep: fragment-linear bf16 permutes. 4096 x 256 threads.
__global__ void prep(const float* __restrict__ w2, const float* __restrict__ w1,
                     const float* __restrict__ wo, const float* __restrict__ b2,
                     ushort* __restrict__ w2p, ushort* __restrict__ w2sp,
                     ushort* __restrict__ w1p, ushort* __restrict__ wop,
                     float* __restrict__ b2t) {
    int i = blockIdx.x * 256 + threadIdx.x;          // 1,048,576 threads
    {   // w2p: channel rows 0..16383. i = cb<<17 | d<<10 | ks<<9 | l<<3 | j
        int j = i & 7, l = (i >> 3) & 63, ks = (i >> 9) & 1;
        int d = (i >> 10) & 127, cb = (i >> 17) & 7;
        w2p[i] = f2b(w2[(size_t)((cb * 16 + (l & 15)) * 128 + d) * 64 +
                        ks * 32 + (l >> 4) * 8 + j]);
    }
    {   // wop: i = kc5<<13 | nb<<9 | l<<3 | j ; k'' = kc5*32 + (l>>4)*8 + j
        int j = i & 7, l = (i >> 3) & 63, nb = (i >> 9) & 15, kc5 = (i >> 13) & 127;
        int o = (l >> 4) * 8 + j, q = nb * 16 + (l & 15);
        int d16 = kc5 & 15, dt2 = kc5 >> 4;
        wop[i] = f2b(wo[(size_t)q * 4096 + o * 128 + dt2 * 16 + d16]);
    }
    if (i < 65536) {  // w2sp: sm rows 16384..17407. i = g<<10 | ks<<9 | l<<3 | j
        int j = i & 7, l = (i >> 3) & 63, ks = (i >> 9) & 1, g = (i >> 10) & 63;
        w2sp[i] = f2b(w2[(size_t)(16384 + g * 16 + (l & 15)) * 64 +
                         ks * 32 + (l >> 4) * 8 + j]);
    }
    if (i < 16384) {  // w1p: i = nb<<12 | ks<<9 | l<<3 | j
        int j = i & 7, l = (i >> 3) & 63, ks = (i >> 9) & 7, nb = i >> 12;
        w1p[i] = f2b(w1[(nb * 16 + (l & 15)) * 256 + ks * 32 + (l >> 4) * 8 + j]);
        b2t[i] = b2[(i & 127) * 128 + (i >> 7)];      // [d][c]
    }
}

// ---------------------------------------------------------------------------
__launch_bounds__(512, 2)
__global__ void fused(const float* __restrict__ sampled, const float* __restrict__ query,
                      const float* __restrict__ ln_w, const float* __restrict__ ln_b,
                      const float* __restrict__ b1, const float* __restrict__ b2,
                      const float* __restrict__ m_beta, const float* __restrict__ s_beta,
                      const ushort* __restrict__ w2p, const ushort* __restrict__ w2sp,
                      const ushort* __restrict__ w1p, const float* __restrict__ b2t,
                      ushort* __restrict__ y2f) {
    __shared__ ushort Hb[TW * 64];                       // h bf16 [t][64]
    __shared__ union {
        ushort qn[TW * 264];                             // phase 1: LN out
        ushort smT[TW * 1032];                           // phase 2: sm [t][o*32+p]
        struct {
            ushort pt[TW * 1032];                        // [t][chunk(c>>3,dd)][c&7]
            ushort g1s[TW * 640];                        // [t][d16*40+p]
        } mp;                                            // main loop
    } U;
    __shared__ float mb_s[128];
    __shared__ float sb_s[32];

    const int tid  = threadIdx.x;
    const int wv   = tid >> 6;          // wave 0..7
    const int lane = tid & 63;
    const int lq   = lane >> 4;         // quad
    const int ln16 = lane & 15;
    const int tok0 = blockIdx.x * TW;

    if (tid < 128) mb_s[tid] = m_beta[tid];
    else if (tid < 160) sb_s[tid - 128] = s_beta[tid - 128];

    // ---- step 1: LayerNorm, 2 tokens per wave; qn -> LDS bf16 (row 264)
    for (int tt = 0; tt < 2; ++tt) {
        int t = wv * 2 + tt;
        const float* q = query + (size_t)(tok0 + t) * 256;
        float2 a = *(const float2*)(q + 2 * lane);
        float2 b = *(const float2*)(q + 128 + 2 * lane);
        float s = a.x + a.y + b.x + b.y;
        for (int off = 1; off < 64; off <<= 1) s += __shfl_xor(s, off);
        float mu = s * (1.0f / 256.0f);
        float d0 = a.x - mu, d1 = a.y - mu, d2 = b.x - mu, d3 = b.y - mu;
        float ss = d0 * d0 + d1 * d1 + d2 * d2 + d3 * d3;
        for (int off = 1; off < 64; off <<= 1) ss += __shfl_xor(ss, off);
        float rstd = rsqrtf(ss * (1.0f / 256.0f) + 1e-6f);
        int i0 = 2 * lane, i1 = 2 * lane + 128;
        float q0 = d0 * rstd * ln_w[i0]     + ln_b[i0];
        float q1 = d1 * rstd * ln_w[i0 + 1] + ln_b[i0 + 1];
        float q2 = d2 * rstd * ln_w[i1]     + ln_b[i1];
        float q3 = d3 * rstd * ln_w[i1 + 1] + ln_b[i1 + 1];
        *(uint32_t*)&U.qn[t * 264 + i0] = pk2(q0, q1);
        *(uint32_t*)&U.qn[t * 264 + i1] = pk2(q2, q3);
    }
    __syncthreads();

    // ---- step 2: h[16 tok][64] = qn @ w1^T + b1 (waves 0..3)
    if (wv < 4) {
        int nb = wv;
        f32x4 acc = {0.0f, 0.0f, 0.0f, 0.0f};
        for (int ks = 0; ks < 8; ++ks) {
            bf16x8 afr = *(const bf16x8*)&U.qn[ln16 * 264 + ks * 32 + lq * 8];
            bf16x8 bfr = *(const bf16x8*)&w1p[(nb * 8 + ks) * 512 + lane * 8];
            acc = __builtin_amdgcn_mfma_f32_16x16x32_bf16(afr, bfr, acc, 0, 0, 0);
        }
        float bias = b1[nb * 16 + ln16];
        for (int i = 0; i < 4; ++i) {
            int t = lq * 4 + i;                      // D row = token
            Hb[t * 64 + nb * 16 + ln16] = f2b(acc[i] + bias);
        }
    }
    __syncthreads();

    // ---- step 3: H B-frags; sm generation -> smT; x A-frag hoist
    bf16x8 hfr[2];
    hfr[0] = *(const bf16x8*)&Hb[ln16 * 64 + 0 + lq * 8];
    hfr[1] = *(const bf16x8*)&Hb[ln16 * 64 + 32 + lq * 8];

    for (int gi = 0; gi < 8; ++gi) {                 // sm rows 16384 + g*16 + m
        int g = wv * 8 + gi;
        f32x4 acc = *(const f32x4*)&b2[16384 + g * 16 + lq * 4];
        for (int ks = 0; ks < 2; ++ks) {
            bf16x8 afr = *(const bf16x8*)&w2sp[(g * 2 + ks) * 512 + lane * 8];
            acc = __builtin_amdgcn_mfma_f32_16x16x32_bf16(afr, hfr[ks], acc, 0, 0, 0);
        }
        int o = g >> 1;
        int p0 = (g & 1) * 16 + lq * 4;
        uint2 wr;
        wr.x = pk2(acc[0], acc[1]);
        wr.y = pk2(acc[2], acc[3]);
        *(uint2*)&U.smT[ln16 * 1032 + o * 32 + p0] = wr;   // token-major
    }

    bf16x8 xa[2][2][4];                              // x A-frags [tt][p-half][ks]
    for (int tt = 0; tt < 2; ++tt) {
        const float* xp = sampled + (size_t)(tok0 + wv * 2 + tt) * 4096;
        for (int mt = 0; mt < 2; ++mt) {
            int p = mt * 16 + ln16;
            for (int ks = 0; ks < 4; ++ks) {
                int c = ks * 32 + lq * 8;
                float4 lo = *(const float4*)(xp + p * 128 + c);
                float4 hi = *(const float4*)(xp + p * 128 + c + 4);
                ushort8 u;
                u[0] = f2b(lo.x); u[1] = f2b(lo.y); u[2] = f2b(lo.z); u[3] = f2b(lo.w);
                u[4] = f2b(hi.x); u[5] = f2b(hi.y); u[6] = f2b(hi.z); u[7] = f2b(hi.w);
                xa[tt][mt][ks] = __builtin_bit_cast(bf16x8, u);
            }
        }
    }
    __syncthreads();

    // ---- step 4: sm A-frags (K=32) for this wave's 2 tokens
    bf16x8 sa[2][2];
    for (int tt = 0; tt < 2; ++tt) {
        int t = wv * 2 + tt;
        for (int mt = 0; mt < 2; ++mt)
            sa[tt][mt] = *(const bf16x8*)&U.smT[t * 1032 + (mt * 16 + ln16) * 32 + lq * 8];
    }
    __syncthreads();    // smT dead; pt/g1s alias it from here on

    // ---- main loop over 16 d-tiles of width 8; spatial every 2nd tile
    for (int dt = 0; dt < 16; ++dt) {
        // GEN: wave wv owns c-block cb=wv; P[c, token] for d = dt*8+dd
        const int cb = wv;
        for (int dd = 0; dd < 8; ++dd) {
            int d = dt * 8 + dd;
            // bias: b2t[d][c], c = cb*16 + lq*4 + i -> one broadcast f32x4
            f32x4 acc = *(const f32x4*)&b2t[d * 128 + cb * 16 + lq * 4];
            for (int ks = 0; ks < 2; ++ks) {
                bf16x8 afr = *(const bf16x8*)&w2p[((cb * 128 + d) * 2 + ks) * 512 + lane * 8];
                acc = __builtin_amdgcn_mfma_f32_16x16x32_bf16(afr, hfr[ks], acc, 0, 0, 0);
            }
            // lane-linear pt: token=ln16, chunk=(c>>3)*8+dd, j=c&7
            uint2 wr;
            wr.x = pk2(acc[0], acc[1]);
            wr.y = pk2(acc[2], acc[3]);
            *(uint2*)&U.mp.pt[ln16 * 1032 + ((cb * 2 + (lq >> 1)) * 8 + dd) * 8 + (lq & 1) * 4] = wr;
        }
        __syncthreads();

        // CONSUME channel: 2 tokens per wave. Lanes n>=8 duplicate n-8's acc;
        // split gelu rows {0,1}/{2,3} across the halves (branchless).
        const int ddl = ln16 & 7;
        const bool hi = ln16 >= 8;
        for (int tt = 0; tt < 2; ++tt) {
            int t = wv * 2 + tt;
            bf16x8 bfr[4];
            for (int ks = 0; ks < 4; ++ks)
                bfr[ks] = *(const bf16x8*)&U.mp.pt[t * 1032 + (ks * 4 + lq) * 64 + ddl * 8];
            float mb = mb_s[dt * 8 + ddl];
            for (int mt = 0; mt < 2; ++mt) {
                f32x4 acc = {0.0f, 0.0f, 0.0f, 0.0f};
                for (int ks = 0; ks < 4; ++ks)
                    acc = __builtin_amdgcn_mfma_f32_16x16x32_bf16(xa[tt][mt][ks], bfr[ks], acc, 0, 0, 0);
                float va = hi ? acc[2] : acc[0];
                float vb = hi ? acc[3] : acc[1];
                float ga = gelu_fast(va + mb);
                float gb = gelu_fast(vb + mb);
                // g1s[t][d16][p]: d16 = (dt&1)*8+ddl; rows p0..p0+1 by lo half,
                // p0+2..p0+3 by hi half
                int p = mt * 16 + lq * 4 + (hi ? 2 : 0);
                *(uint32_t*)&U.mp.g1s[t * 640 + ((dt & 1) * 8 + ddl) * 40 + p] = pk2(ga, gb);
            }
        }

        // SPATIAL on odd dt: full 16-lane n over paired d16 = 0..15
        if (dt & 1) {
            __builtin_amdgcn_wave_barrier();          // order same-wave LDS W->R
            int dt2 = dt >> 1;
            for (int tt = 0; tt < 2; ++tt) {
                int t = wv * 2 + tt;
                bf16x8 gb = *(const bf16x8*)&U.mp.g1s[t * 640 + ln16 * 40 + lq * 8];
                for (int mt = 0; mt < 2; ++mt) {
                    f32x4 acc = {0.0f, 0.0f, 0.0f, 0.0f};
                    acc = __builtin_amdgcn_mfma_f32_16x16x32_bf16(sa[tt][mt], gb, acc, 0, 0, 0);
                    float4 sbv = *(const float4*)&sb_s[mt * 16 + lq * 4];
                    float g0 = gelu_fast(acc[0] + sbv.x);
                    float g1 = gelu_fast(acc[1] + sbv.y);
                    float g2 = gelu_fast(acc[2] + sbv.z);
                    float g3 = gelu_fast(acc[3] + sbv.w);
                    uint2 wr;
                    wr.x = pk2(g0, g1);
                    wr.y = pk2(g2, g3);
                    // y2f A-frag-linear: kc5 = dt2*16 + d16(=ln16),
                    // l = t + (o>>3)*16, j = o&7; o = mt*16 + lq*4 + i
                    size_t addr = (size_t)blockIdx.x * 65536 +
                                  (dt2 * 16 + ln16) * 512 +
                                  (t + (mt * 2 + (lq >> 1)) * 16) * 8 + (lq & 1) * 4;
                    *(uint2*)&y2f[addr] = wr;
                }
            }
        }
        __syncthreads();
    }
}

// ---------------------------------------------------------------------------
// outproj R5: out[8192,256] = y2f (A-frag) @ wop (B-frag) + bo.
// 256 blocks x 512 thr. Wave wv owns 32 tokens x 32 q (nb = 2wv, 2wv+1),
// FULL K (128 kc5 steps). acc[2][2] f32x4 = 16 VGPRs -> no spill.
// 4 lane-linear 1KB loads per 4 MFMA. Direct stores, no LDS, no atomics.
__launch_bounds__(512, 2)
__global__ void outproj(const ushort* __restrict__ y2f, const ushort* __restrict__ wop,
                        const float* __restrict__ bo, float* __restrict__ out) {
    const int tid  = threadIdx.x;
    const int wv   = tid >> 6;
    const int lane = tid & 63;
    const int lq   = lane >> 4;
    const int ln16 = lane & 15;
    const int tb   = blockIdx.x;                     // 32-token block

    f32x4 acc[2][2];
    for (int m = 0; m < 2; ++m)
        for (int n = 0; n < 2; ++n) acc[m][n] = (f32x4){0.0f, 0.0f, 0.0f, 0.0f};

    const ushort* a0 = y2f + (size_t)(tb * 2) * 65536 + lane * 8;     // tokens tb*32..+15
    const ushort* a1 = a0 + 65536;                                    // tokens +16..31
    const ushort* bp = wop + (size_t)(wv * 2) * 512 + lane * 8;       // nb = 2wv

    #pragma unroll 4
    for (int k = 0; k < 128; ++k) {
        bf16x8 af0 = *(const bf16x8*)(a0 + k * 512);
        bf16x8 af1 = *(const bf16x8*)(a1 + k * 512);
        bf16x8 bf0 = *(const bf16x8*)(bp + (size_t)k * 8192);
        bf16x8 bf1 = *(const bf16x8*)(bp + (size_t)k * 8192 + 512);
        acc[0][0] = __builtin_amdgcn_mfma_f32_16x16x32_bf16(af0, bf0, acc[0][0], 0, 0, 0);
        acc[0][1] = __builtin_amdgcn_mfma_f32_16x16x32_bf16(af0, bf1, acc[0][1], 0, 0, 0);
        acc[1][0] = __builtin_amdgcn_mfma_f32_16x16x32_bf16(af1, bf0, acc[1][0], 0, 0, 0);
        acc[1][1] = __builtin_amdgcn_mfma_f32_16x16x32_bf16(af1, bf1, acc[1][1], 0, 0, 0);
    }

    for (int n = 0; n < 2; ++n) {
        int q = (wv * 2 + n) * 16 + ln16;
        float bov = bo[q];
        for (int m = 0; m < 2; ++m)
            for (int i = 0; i < 4; ++i) {
                int tok = tb * 32 + m * 16 + lq * 4 + i;   // D row = token
                out[(size_t)tok * 256 + q] = acc[m][n][i] + bov;
            }
    }
}

// ---------------------------------------------------------------------------
extern "C" void kernel_launch(void* const* d_in, const int* in_sizes, int n_in,
                              void* d_out, int out_size, void* d_ws, size_t ws_size,
                              hipStream_t stream) {
    const float* sampled = (const float*)d_in[0];
    const float* query   = (const float*)d_in[1];
    const float* ln_w    = (const float*)d_in[2];
    const float* ln_b    = (const float*)d_in[3];
    const float* w1      = (const float*)d_in[4];
    const float* b1      = (const float*)d_in[5];
    const float* w2      = (const float*)d_in[6];
    const float* b2      = (const float*)d_in[7];
    const float* m_beta  = (const float*)d_in[8];
    const float* s_beta  = (const float*)d_in[9];
    const float* wo      = (const float*)d_in[10];
    const float* bo      = (const float*)d_in[11];
    float* out = (float*)d_out;

    char* ws = (char*)d_ws;
    ushort* w2p  = (ushort*)(ws);                   // 2,097,152 B
    ushort* wop  = (ushort*)(ws + 2097152);         // 2,097,152 B
    ushort* w2sp = (ushort*)(ws + 4194304);         //   131,072 B
    ushort* w1p  = (ushort*)(ws + 4325376);         //    32,768 B
    float*  b2t  = (float*) (ws + 4358144);         //    65,536 B
    ushort* y2f  = (ushort*)(ws + 4423680);         // 67,108,864 B (total ~68.2 MB)

    prep<<<4096, 256, 0, stream>>>(w2, w1, wo, b2, w2p, w2sp, w1p, wop, b2t);
    fused<<<512, 512, 0, stream>>>(sampled, query, ln_w, ln_b, b1, b2,
                                   m_beta, s_beta, w2p, w2sp, w1p, b2t, y2f);
    outproj<<<256, 512, 0, stream>>>(y2f, wop, bo, out);
}